// Round 2
// baseline (497.059 us; speedup 1.0000x reference)
//
#include <hip/hip_runtime.h>
#include <math.h>

typedef unsigned short u16;
typedef unsigned short u16x8 __attribute__((ext_vector_type(8)));
typedef unsigned short u16x4 __attribute__((ext_vector_type(4)));
typedef _Float16 f16x8 __attribute__((ext_vector_type(8)));
typedef float f32x4 __attribute__((ext_vector_type(4)));

#define LOG2E 1.4426950408889634f

static __device__ __forceinline__ u16 f2h(float f) { return __builtin_bit_cast(u16, (_Float16)f); }
static __device__ __forceinline__ float h2f(u16 u) { return (float)__builtin_bit_cast(_Float16, u); }

// async global->LDS, 16B per lane; LDS dest = wave-uniform base + lane*16
static __device__ __forceinline__ void g2l16(const u16* g, u16* l) {
    __builtin_amdgcn_global_load_lds(
        (const __attribute__((address_space(1))) void*)g,
        (__attribute__((address_space(3))) void*)l, 16, 0, 0);
}

static __device__ __forceinline__ u16x8 ld8f(const float* p) {
    f32x4 a = *(const f32x4*)p;
    f32x4 b = *(const f32x4*)(p + 4);
    u16x8 r;
    r[0] = f2h(a[0]); r[1] = f2h(a[1]); r[2] = f2h(a[2]); r[3] = f2h(a[3]);
    r[4] = f2h(b[0]); r[5] = f2h(b[1]); r[6] = f2h(b[2]); r[7] = f2h(b[3]);
    return r;
}

// ---------------------------------------------------------------------------
// fused fp32->f16 convert: hs (4096 blk) + Wq + Wk + Wv (2048 blk each)
// ---------------------------------------------------------------------------
__global__ __launch_bounds__(256) void cvt4(
    const float* __restrict__ hs, const float* __restrict__ Wq,
    const float* __restrict__ Wk, const float* __restrict__ Wv,
    u16* __restrict__ hs16, u16* __restrict__ wq16,
    u16* __restrict__ wk16, u16* __restrict__ wv16)
{
    int blk = blockIdx.x;
    const float* s; u16* d;
    if (blk < 4096)      { s = hs; d = hs16; }
    else if (blk < 6144) { s = Wq; d = wq16; blk -= 4096; }
    else if (blk < 8192) { s = Wk; d = wk16; blk -= 6144; }
    else                 { s = Wv; d = wv16; blk -= 8192; }
    const size_t e = ((size_t)blk * 256 + threadIdx.x) * 8;
    *(u16x8*)(d + e) = ld8f(s + e);
}

__global__ __launch_bounds__(256) void cvt1(const float* __restrict__ s, u16* __restrict__ d) {
    const size_t e = ((size_t)blockIdx.x * 256 + threadIdx.x) * 8;
    *(u16x8*)(d + e) = ld8f(s + e);
}

// ---------------------------------------------------------------------------
// QKV GEMM v2: triple-buffered counted-vmcnt pipeline.
// DMA for tile t+2 issued at top of iter t; ONE boundary sync per tile:
// s_waitcnt vmcnt(4) (tile t+1 landed, t+2's 4 loads stay in flight) +
// raw s_barrier + sched_barrier(0). No intra-tile barriers (staging is pure
// DMA; every ds_read is consumed by this tile's MFMAs). Addressing/swizzle
// identical to verified v1. LDS 48 KB -> 3 blocks/CU.
// z=0->Q, 1->K ([b*s][h*d]); z=2->V transposed [b,h,d,s].
// ---------------------------------------------------------------------------
__global__ __launch_bounds__(256, 4) void gemm_qkv(
    const u16* __restrict__ A,
    const u16* __restrict__ W0, const u16* __restrict__ W1, const u16* __restrict__ W2,
    const float* __restrict__ B0, const float* __restrict__ B1, const float* __restrict__ B2,
    u16* __restrict__ Cq, u16* __restrict__ Ck, u16* __restrict__ Cvt)
{
    constexpr int K = 2048, N = 2048, NT = K / 32;
    const int z = blockIdx.z;
    const u16* W      = (z == 0) ? W0 : ((z == 1) ? W1 : W2);
    const float* bias = (z == 0) ? B0 : ((z == 1) ? B1 : B2);
    const int m0 = blockIdx.y * 128, n0 = blockIdx.x * 128;

    __shared__ __attribute__((aligned(16))) u16 As[3][128 * 32];
    __shared__ __attribute__((aligned(16))) u16 Bs[3][128 * 32];

    const int tid = threadIdx.x, l = tid & 63, w = tid >> 6;
    const int quad = l >> 4, lan = l & 15;

    // staging: wave w covers rows [w*32, w*32+32), source col-group XOR'd by row>>2
    const int sr = l >> 2, gcol = l & 3;
    const int gs0 = (gcol ^ ((w * 8 + (sr >> 2)) & 3)) * 8;
    const int gs1 = (gcol ^ ((w * 8 + 4 + (sr >> 2)) & 3)) * 8;
    const u16* pA0 = A + (size_t)(m0 + w * 32 + sr) * K + gs0;
    const u16* pA1 = A + (size_t)(m0 + w * 32 + 16 + sr) * K + gs1;
    const u16* pB0 = W + (size_t)(n0 + w * 32 + sr) * K + gs0;
    const u16* pB1 = W + (size_t)(n0 + w * 32 + 16 + sr) * K + gs1;
    const int dA0 = (w * 32) * 32;
    const int dA1 = (w * 32 + 16) * 32;

    const int wm = (w >> 1) * 64, wn = (w & 1) * 64;
    const int swq = (quad ^ ((lan >> 2) & 3)) * 8;

    f32x4 acc[4][4] = {};

    // prologue: tiles 0 and 1 in flight; wait tile 0 (leave tile 1's 4 loads)
    {
        g2l16(pA0, &As[0][dA0]); g2l16(pA1, &As[0][dA1]);
        g2l16(pB0, &Bs[0][dA0]); g2l16(pB1, &Bs[0][dA1]);
        g2l16(pA0 + 32, &As[1][dA0]); g2l16(pA1 + 32, &As[1][dA1]);
        g2l16(pB0 + 32, &Bs[1][dA0]); g2l16(pB1 + 32, &Bs[1][dA1]);
    }
    __asm__ volatile("s_waitcnt vmcnt(4)" ::: "memory");
    __builtin_amdgcn_s_barrier();
    __builtin_amdgcn_sched_barrier(0);

    int bc = 0;                         // buffer of current tile
    for (int t = 0; t < NT; ++t) {
        int bi = bc + 2; if (bi >= 3) bi -= 3;     // buffer of tile t+2
        if (t + 2 < NT) {
            const int kk = (t + 2) * 32;
            g2l16(pA0 + kk, &As[bi][dA0]); g2l16(pA1 + kk, &As[bi][dA1]);
            g2l16(pB0 + kk, &Bs[bi][dA0]); g2l16(pB1 + kk, &Bs[bi][dA1]);
        }

        const u16* Ab = As[bc];
        const u16* Bb = Bs[bc];
        f16x8 af[4], bf[4];
#pragma unroll
        for (int i = 0; i < 4; i++)
            af[i] = __builtin_bit_cast(f16x8, *(const u16x8*)(&Ab[(wm + i * 16 + lan) * 32 + swq]));
#pragma unroll
        for (int j = 0; j < 4; j++)
            bf[j] = __builtin_bit_cast(f16x8, *(const u16x8*)(&Bb[(wn + j * 16 + lan) * 32 + swq]));

        __builtin_amdgcn_s_setprio(1);
#pragma unroll
        for (int i = 0; i < 4; i++)
#pragma unroll
            for (int j = 0; j < 4; j++)
                acc[i][j] = __builtin_amdgcn_mfma_f32_16x16x32_f16(af[i], bf[j], acc[i][j], 0, 0, 0);
        __builtin_amdgcn_s_setprio(0);

        if (t + 1 < NT) {
            if (t + 2 < NT) { __asm__ volatile("s_waitcnt vmcnt(4)" ::: "memory"); }
            else            { __asm__ volatile("s_waitcnt vmcnt(0)" ::: "memory"); }
            __builtin_amdgcn_s_barrier();
            __builtin_amdgcn_sched_barrier(0);
        }
        bc = (bc == 2) ? 0 : bc + 1;
    }

    if (z < 2) {
        u16* C = (z == 0) ? Cq : Ck;
#pragma unroll
        for (int j = 0; j < 4; j++) {
            const int col = n0 + wn + j * 16 + lan;
            const float bj = bias[col];
#pragma unroll
            for (int i = 0; i < 4; i++)
#pragma unroll
                for (int r = 0; r < 4; r++) {
                    const int row = m0 + wm + i * 16 + quad * 4 + r;
                    C[(size_t)row * N + col] = f2h(acc[i][j][r] + bj);
                }
        }
    } else {
        // V transposed: row=(b,s), col=(h,d) -> Cvt[((b*16+h)*128+d)*2048 + s]
        // 4 consecutive s per (i,j) -> packed 8B stores
#pragma unroll
        for (int j = 0; j < 4; j++) {
            const int col = n0 + wn + j * 16 + lan;
            const int hh = col >> 7, dd = col & 127;
            const float bj = bias[col];
            u16* Cr = Cvt + ((size_t)hh * 128 + dd) * 2048;
#pragma unroll
            for (int i = 0; i < 4; i++) {
                const int row0 = m0 + wm + i * 16 + quad * 4;
                const int bb = row0 >> 11, ss = row0 & 2047;
                u16x4 pv;
#pragma unroll
                for (int r = 0; r < 4; r++) pv[r] = f2h(acc[i][j][r] + bj);
                *(u16x4*)(Cr + (size_t)bb * 4194304 + ss) = pv;
            }
        }
    }
}

// ---------------------------------------------------------------------------
// RMSNorm + RoPE + history key scale; in-place f16 q/k; q *= 1/sqrt(128).
// ---------------------------------------------------------------------------
__global__ __launch_bounds__(256) void norm_rope(
    u16* __restrict__ q, u16* __restrict__ k,
    const float* __restrict__ rot,
    const float* __restrict__ nqw, const float* __restrict__ nkw,
    const float* __restrict__ hks, const int* __restrict__ oclp)
{
    const int row = blockIdx.x;
    const int s = row & 2047;
    const int t = threadIdx.x;
    const size_t base = (size_t)row * 2048 + t * 8;

    u16x8 q8 = *(const u16x8*)(q + base);
    u16x8 k8 = *(const u16x8*)(k + base);

    float qf[8], kf[8];
    float sq = 0.f, sk = 0.f;
#pragma unroll
    for (int i = 0; i < 8; i++) {
        qf[i] = h2f(q8[i]); sq += qf[i] * qf[i];
        kf[i] = h2f(k8[i]); sk += kf[i] * kf[i];
    }
#pragma unroll
    for (int off = 32; off > 0; off >>= 1) {
        sq += __shfl_down(sq, off);
        sk += __shfl_down(sk, off);
    }
    __shared__ float rq[4], rk[4];
    const int wv = t >> 6;
    if ((t & 63) == 0) { rq[wv] = sq; rk[wv] = sk; }
    __syncthreads();
    const float tq = rq[0] + rq[1] + rq[2] + rq[3];
    const float tk = rk[0] + rk[1] + rk[2] + rk[3];
    const float scq = rsqrtf(tq * (1.0f / 2048.0f) + 1e-5f);
    const float sck = rsqrtf(tk * (1.0f / 2048.0f) + 1e-5f);
#pragma unroll
    for (int i = 0; i < 8; i++) {
        qf[i] *= scq * nqw[t * 8 + i];
        kf[i] *= sck * nkw[t * 8 + i];
    }
    const int e0 = t * 8;
    const int dh0 = e0 & 127;
    const int h = e0 >> 7;
    float qo[8], ko[8];
#pragma unroll
    for (int p = 0; p < 4; p++) {
        const int dh = dh0 + 2 * p;
        const float c  = rot[s * 256 + dh];
        const float sn = rot[s * 256 + 128 + dh + 1];
        qo[2 * p]     = qf[2 * p] * c  - qf[2 * p + 1] * sn;
        qo[2 * p + 1] = qf[2 * p] * sn + qf[2 * p + 1] * c;
        ko[2 * p]     = kf[2 * p] * c  - kf[2 * p + 1] * sn;
        ko[2 * p + 1] = kf[2 * p] * sn + kf[2 * p + 1] * c;
    }
    const float ATT = 0.08838834764831845f;
#pragma unroll
    for (int i = 0; i < 8; i++) qo[i] *= ATT;

    const int hist = 2048 - oclp[0];
    if (s < hist) {
        const float hv = hks[h];
        const float scl = 1.0f + 9.0f / (1.0f + expf(-hv));
#pragma unroll
        for (int i = 0; i < 8; i++) ko[i] *= scl;
    }

    u16x8 qo8, ko8;
#pragma unroll
    for (int i = 0; i < 8; i++) { qo8[i] = f2h(qo[i]); ko8[i] = f2h(ko[i]); }
    *(u16x8*)(q + base) = qo8;
    *(u16x8*)(k + base) = ko8;
}

// ---------------------------------------------------------------------------
// Flash attention v5: swapped-operand MFMAs (unchanged from round 1).
// ---------------------------------------------------------------------------
__global__ __launch_bounds__(256, 4) void flash_attn5(
    const u16* __restrict__ Q, const u16* __restrict__ Kr, const u16* __restrict__ Vt,
    u16* __restrict__ O)
{
    const int qt = blockIdx.x;        // 0..31 (64 q-rows each)
    const int bh = blockIdx.y;        // 0..31
    const int b = bh >> 4, h = bh & 15;
    const int tid = threadIdx.x, l = tid & 63, w = tid >> 6;
    const int quad = l >> 4, lan = l & 15;

    __shared__ __attribute__((aligned(16))) u16 Kb[2][32 * 128];
    __shared__ __attribute__((aligned(16))) u16 VTb[2][128 * 32];
    __shared__ __attribute__((aligned(16))) u16 Pb[4][16 * 40];

    // Q frags (q pre-scaled by 1/sqrt(128)); used as B-operand (Q^T)
    f16x8 qf[4];
    {
        const u16* qp = Q + ((size_t)(b * 2048 + qt * 64 + w * 16 + lan)) * 2048 + h * 128 + quad * 8;
#pragma unroll
        for (int ks = 0; ks < 4; ks++)
            qf[ks] = __builtin_bit_cast(f16x8, *(const u16x8*)(qp + ks * 32));
    }

    const int krow_b = w * 4 + (l >> 4);           // +16i per issue
    const int kchk   = l & 15;
    const u16* kbase = Kr + ((size_t)(b * 2048)) * 2048 + h * 128;
    const int vrow_b = w * 16 + (l >> 2);          // +64i per issue
    const int vg     = ((l & 3) ^ ((l >> 3) & 3)) * 8;
    const u16* vbase = Vt + ((size_t)((b * 16 + h) * 128)) * 2048;

    float mr = -3.0e38f, lrp = 0.f;
    f32x4 o[8] = {};

    // issue DMA for tile 0 into buf 0
#pragma unroll
    for (int i = 0; i < 2; i++) {
        const int kr = krow_b + 16 * i;
        g2l16(kbase + (size_t)kr * 2048 + ((kchk ^ (kr & 15)) * 8), &Kb[0][(w * 64 + 256 * i) * 8]);
    }
#pragma unroll
    for (int i = 0; i < 2; i++) {
        const int vr = vrow_b + 64 * i;
        g2l16(vbase + (size_t)vr * 2048 + vg, &VTb[0][(w * 64 + 256 * i) * 8]);
    }
    __syncthreads();   // drain tile-0 DMA

    for (int kt = 0; kt < 64; kt++) {
        const int buf = kt & 1;
        // prefetch tile kt+1 into other buffer (completes during compute)
        if (kt < 63) {
            const int kn = (kt + 1) * 32;
#pragma unroll
            for (int i = 0; i < 2; i++) {
                const int kr = krow_b + 16 * i;
                g2l16(kbase + (size_t)(kn + kr) * 2048 + ((kchk ^ (kr & 15)) * 8),
                      &Kb[buf ^ 1][(w * 64 + 256 * i) * 8]);
            }
#pragma unroll
            for (int i = 0; i < 2; i++) {
                const int vr = vrow_b + 64 * i;
                g2l16(vbase + (size_t)vr * 2048 + kn + vg,
                      &VTb[buf ^ 1][(w * 64 + 256 * i) * 8]);
            }
        }

        // S^T = K Q^T  (32 k-rows x 16 q-cols per wave); lane: q=lan,
        // k = nt*16 + quad*4 + r
        f32x4 sfr[2] = {};
        __builtin_amdgcn_s_setprio(1);
#pragma unroll
        for (int ks = 0; ks < 4; ks++)
#pragma unroll
            for (int nt = 0; nt < 2; nt++) {
                f16x8 kb = __builtin_bit_cast(f16x8, *(const u16x8*)(
                    &Kb[buf][(nt * 16 + lan) * 128 + (((ks * 4 + quad) ^ lan) * 8)]));
                sfr[nt] = __builtin_amdgcn_mfma_f32_16x16x32_f16(kb, qf[ks], sfr[nt], 0, 0, 0);
            }
        __builtin_amdgcn_s_setprio(0);

        // per-lane scalar online softmax over this tile's 32 k's
        float tm = fmaxf(fmaxf(fmaxf(sfr[0][0], sfr[0][1]), fmaxf(sfr[0][2], sfr[0][3])),
                         fmaxf(fmaxf(sfr[1][0], sfr[1][1]), fmaxf(sfr[1][2], sfr[1][3])));
        tm = fmaxf(tm, __shfl_xor(tm, 16));
        tm = fmaxf(tm, __shfl_xor(tm, 32));

        if (!__all(tm <= mr + 4.0f)) {       // defer-max: rescale only on growth
            const float nm = fmaxf(mr, tm);
            const float al = exp2f((mr - nm) * LOG2E);
            mr = nm;
            lrp *= al;
#pragma unroll
            for (int nd = 0; nd < 8; nd++)
#pragma unroll
                for (int r = 0; r < 4; r++) o[nd][r] *= al;
        }

        float ps = 0.f;
        u16x4 p0, p1;
#pragma unroll
        for (int r = 0; r < 4; r++) {
            const float p = exp2f((sfr[0][r] - mr) * LOG2E);
            ps += p; p0[r] = f2h(p);
        }
#pragma unroll
        for (int r = 0; r < 4; r++) {
            const float p = exp2f((sfr[1][r] - mr) * LOG2E);
            ps += p; p1[r] = f2h(p);
        }
        lrp += ps;

        // stage P[q=lan][k]: two b64 writes (4 consecutive k each)
        *(u16x4*)(&Pb[w][lan * 40 + quad * 4])      = p0;
        *(u16x4*)(&Pb[w][lan * 40 + 16 + quad * 4]) = p1;

        __asm__ volatile("s_waitcnt lgkmcnt(0)" ::: "memory");  // own-wave P visible

        // O^T += V^T P^T : one mfma per 16-d block
        f16x8 pf = __builtin_bit_cast(f16x8, *(const u16x8*)(&Pb[w][lan * 40 + quad * 8]));
        __builtin_amdgcn_s_setprio(1);
#pragma unroll
        for (int nd = 0; nd < 8; nd++) {
            f16x8 vtf = __builtin_bit_cast(f16x8, *(const u16x8*)(
                &VTb[buf][(nd * 16 + lan) * 32 + ((quad ^ ((lan >> 1) & 3)) * 8)]));
            o[nd] = __builtin_amdgcn_mfma_f32_16x16x32_f16(vtf, pf, o[nd], 0, 0, 0);
        }
        __builtin_amdgcn_s_setprio(0);

        __syncthreads();   // drains kt+1 DMA (had full compute to land) + syncs
    }

    // finalize: sum l across quads (each quad summed a disjoint k-subset)
    lrp += __shfl_xor(lrp, 16);
    lrp += __shfl_xor(lrp, 32);
    const float inv = 1.0f / lrp;

    // O^T lane layout: q = lan, d = nd*16 + quad*4 + r -> 4 consecutive d
    u16* Or = O + ((size_t)(b * 2048 + qt * 64 + w * 16 + lan)) * 2048 + h * 128 + quad * 4;
#pragma unroll
    for (int nd = 0; nd < 8; nd++) {
        u16x4 ov;
#pragma unroll
        for (int r = 0; r < 4; r++) ov[r] = f2h(o[nd][r] * inv);
        *(u16x4*)(Or + nd * 16) = ov;
    }
}

// ---------------------------------------------------------------------------
// Output projection v2: same triple-buffered counted-vmcnt pipeline.
// A = aout f16, B = Wo16 f16, C fp32.
// ---------------------------------------------------------------------------
__global__ __launch_bounds__(256, 4) void gemm_out(
    const u16* __restrict__ A, const u16* __restrict__ W,
    const float* __restrict__ bias, float* __restrict__ C)
{
    constexpr int K = 2048, N = 2048, NT = K / 32;
    const int m0 = blockIdx.y * 128, n0 = blockIdx.x * 128;

    __shared__ __attribute__((aligned(16))) u16 As[3][128 * 32];
    __shared__ __attribute__((aligned(16))) u16 Bs[3][128 * 32];

    const int tid = threadIdx.x, l = tid & 63, w = tid >> 6;
    const int quad = l >> 4, lan = l & 15;

    const int sr = l >> 2, gcol = l & 3;
    const int gs0 = (gcol ^ ((w * 8 + (sr >> 2)) & 3)) * 8;
    const int gs1 = (gcol ^ ((w * 8 + 4 + (sr >> 2)) & 3)) * 8;
    const u16* pA0 = A + (size_t)(m0 + w * 32 + sr) * K + gs0;
    const u16* pA1 = A + (size_t)(m0 + w * 32 + 16 + sr) * K + gs1;
    const u16* pB0 = W + (size_t)(n0 + w * 32 + sr) * K + gs0;
    const u16* pB1 = W + (size_t)(n0 + w * 32 + 16 + sr) * K + gs1;
    const int dA0 = (w * 32) * 32;
    const int dA1 = (w * 32 + 16) * 32;

    const int wm = (w >> 1) * 64, wn = (w & 1) * 64;
    const int swq = (quad ^ ((lan >> 2) & 3)) * 8;

    f32x4 acc[4][4] = {};

    {
        g2l16(pA0, &As[0][dA0]); g2l16(pA1, &As[0][dA1]);
        g2l16(pB0, &Bs[0][dA0]); g2l16(pB1, &Bs[0][dA1]);
        g2l16(pA0 + 32, &As[1][dA0]); g2l16(pA1 + 32, &As[1][dA1]);
        g2l16(pB0 + 32, &Bs[1][dA0]); g2l16(pB1 + 32, &Bs[1][dA1]);
    }
    __asm__ volatile("s_waitcnt vmcnt(4)" ::: "memory");
    __builtin_amdgcn_s_barrier();
    __builtin_amdgcn_sched_barrier(0);

    int bc = 0;
    for (int t = 0; t < NT; ++t) {
        int bi = bc + 2; if (bi >= 3) bi -= 3;
        if (t + 2 < NT) {
            const int kk = (t + 2) * 32;
            g2l16(pA0 + kk, &As[bi][dA0]); g2l16(pA1 + kk, &As[bi][dA1]);
            g2l16(pB0 + kk, &Bs[bi][dA0]); g2l16(pB1 + kk, &Bs[bi][dA1]);
        }

        const u16* Ab = As[bc];
        const u16* Bb = Bs[bc];
        f16x8 af[4], bf[4];
#pragma unroll
        for (int i = 0; i < 4; i++)
            af[i] = __builtin_bit_cast(f16x8, *(const u16x8*)(&Ab[(wm + i * 16 + lan) * 32 + swq]));
#pragma unroll
        for (int j = 0; j < 4; j++)
            bf[j] = __builtin_bit_cast(f16x8, *(const u16x8*)(&Bb[(wn + j * 16 + lan) * 32 + swq]));

        __builtin_amdgcn_s_setprio(1);
#pragma unroll
        for (int i = 0; i < 4; i++)
#pragma unroll
            for (int j = 0; j < 4; j++)
                acc[i][j] = __builtin_amdgcn_mfma_f32_16x16x32_f16(af[i], bf[j], acc[i][j], 0, 0, 0);
        __builtin_amdgcn_s_setprio(0);

        if (t + 1 < NT) {
            if (t + 2 < NT) { __asm__ volatile("s_waitcnt vmcnt(4)" ::: "memory"); }
            else            { __asm__ volatile("s_waitcnt vmcnt(0)" ::: "memory"); }
            __builtin_amdgcn_s_barrier();
            __builtin_amdgcn_sched_barrier(0);
        }
        bc = (bc == 2) ? 0 : bc + 1;
    }

#pragma unroll
    for (int j = 0; j < 4; j++) {
        const int col = n0 + wn + j * 16 + lan;
        const float bj = bias[col];
#pragma unroll
        for (int i = 0; i < 4; i++)
#pragma unroll
            for (int r = 0; r < 4; r++) {
                const int row = m0 + wm + i * 16 + quad * 4 + r;
                C[(size_t)row * N + col] = acc[i][j][r] + bj;
            }
    }
}

// ---------------------------------------------------------------------------
extern "C" void kernel_launch(void* const* d_in, const int* in_sizes, int n_in,
                              void* d_out, int out_size, void* d_ws, size_t ws_size,
                              hipStream_t stream) {
    const float* hs  = (const float*)d_in[0];
    const float* rot = (const float*)d_in[1];
    const float* Wq  = (const float*)d_in[2];
    const float* bq  = (const float*)d_in[3];
    const float* Wk  = (const float*)d_in[4];
    const float* bk  = (const float*)d_in[5];
    const float* Wv  = (const float*)d_in[6];
    const float* bv  = (const float*)d_in[7];
    const float* nqw = (const float*)d_in[8];
    const float* nkw = (const float*)d_in[9];
    const float* hks = (const float*)d_in[10];
    const float* Wo  = (const float*)d_in[11];
    const float* bo  = (const float*)d_in[12];
    const int*   ocl = (const int*)d_in[13];

    // ws (64 MiB): [0:16) qraw | [16:32) kraw | [32:48) vtr | [48:64) aout
    // aout region holds Wq16/Wk16 until flash overwrites it (they're dead then).
    u16* qraw = (u16*)d_ws;
    u16* kraw = qraw + 8388608;
    u16* vtr  = kraw + 8388608;
    u16* aout = vtr + 8388608;
    u16* wq16 = aout;                  // [48:56 MiB)
    u16* wk16 = aout + 4194304;        // [56:64 MiB)
    u16* wo16 = qraw;                  // reuses qraw AFTER flash
    float* out = (float*)d_out;
    u16* hs16 = (u16*)d_out;           // d_out [0:16 MiB)
    u16* wv16 = hs16 + 8388608;        // d_out [16:24 MiB)

    // 0) convert hs + Wq/Wk/Wv to f16
    cvt4<<<dim3(10240), 256, 0, stream>>>(hs, Wq, Wk, Wv, hs16, wq16, wk16, wv16);
    // 1) QKV projection (triple-buffered counted-vmcnt); z=2 writes V^T
    gemm_qkv<<<dim3(16, 32, 3), 256, 0, stream>>>(
        hs16, wq16, wk16, wv16, bq, bk, bv, qraw, kraw, vtr);
    // 2) rmsnorm + rope + history scale
    norm_rope<<<dim3(4096), 256, 0, stream>>>(qraw, kraw, rot, nqw, nkw, hks, ocl);
    // 3) flash attention v5 (swapped-operand, 4 blocks/CU) -> aout
    flash_attn5<<<dim3(32, 32), 256, 0, stream>>>(qraw, kraw, vtr, aout);
    // 4) Wo -> f16 into dead qraw region, then output projection -> d_out
    cvt1<<<dim3(2048), 256, 0, stream>>>(Wo, wo16);
    gemm_out<<<dim3(16, 32), 256, 0, stream>>>(aout, wo16, bo, out);
}

// Round 3
// 483.624 us; speedup vs baseline: 1.0278x; 1.0278x over previous
//
#include <hip/hip_runtime.h>
#include <math.h>

typedef unsigned short u16;
typedef unsigned short u16x8 __attribute__((ext_vector_type(8)));
typedef unsigned short u16x4 __attribute__((ext_vector_type(4)));
typedef _Float16 f16x8 __attribute__((ext_vector_type(8)));
typedef float f32x4 __attribute__((ext_vector_type(4)));

#define LOG2E 1.4426950408889634f

static __device__ __forceinline__ u16 f2h(float f) { return __builtin_bit_cast(u16, (_Float16)f); }
static __device__ __forceinline__ float h2f(u16 u) { return (float)__builtin_bit_cast(_Float16, u); }

// async global->LDS, 16B per lane; LDS dest = wave-uniform base + lane*16
static __device__ __forceinline__ void g2l16(const u16* g, u16* l) {
    __builtin_amdgcn_global_load_lds(
        (const __attribute__((address_space(1))) void*)g,
        (__attribute__((address_space(3))) void*)l, 16, 0, 0);
}

static __device__ __forceinline__ u16x8 ld8f(const float* p) {
    f32x4 a = *(const f32x4*)p;
    f32x4 b = *(const f32x4*)(p + 4);
    u16x8 r;
    r[0] = f2h(a[0]); r[1] = f2h(a[1]); r[2] = f2h(a[2]); r[3] = f2h(a[3]);
    r[4] = f2h(b[0]); r[5] = f2h(b[1]); r[6] = f2h(b[2]); r[7] = f2h(b[3]);
    return r;
}

// ---------------------------------------------------------------------------
// fused fp32->f16 convert: hs (4096 blk) + Wq + Wk + Wv (2048 blk each)
// ---------------------------------------------------------------------------
__global__ __launch_bounds__(256) void cvt4(
    const float* __restrict__ hs, const float* __restrict__ Wq,
    const float* __restrict__ Wk, const float* __restrict__ Wv,
    u16* __restrict__ hs16, u16* __restrict__ wq16,
    u16* __restrict__ wk16, u16* __restrict__ wv16)
{
    int blk = blockIdx.x;
    const float* s; u16* d;
    if (blk < 4096)      { s = hs; d = hs16; }
    else if (blk < 6144) { s = Wq; d = wq16; blk -= 4096; }
    else if (blk < 8192) { s = Wk; d = wk16; blk -= 6144; }
    else                 { s = Wv; d = wv16; blk -= 8192; }
    const size_t e = ((size_t)blk * 256 + threadIdx.x) * 8;
    *(u16x8*)(d + e) = ld8f(s + e);
}

__global__ __launch_bounds__(256) void cvt1(const float* __restrict__ s, u16* __restrict__ d) {
    const size_t e = ((size_t)blockIdx.x * 256 + threadIdx.x) * 8;
    *(u16x8*)(d + e) = ld8f(s + e);
}

// ---------------------------------------------------------------------------
// QKV GEMM v2: triple-buffered counted-vmcnt pipeline (unchanged from R2).
// z=0->Q, 1->K ([b*s][h*d]); z=2->V transposed [b,h,d,s].
// ---------------------------------------------------------------------------
__global__ __launch_bounds__(256, 4) void gemm_qkv(
    const u16* __restrict__ A,
    const u16* __restrict__ W0, const u16* __restrict__ W1, const u16* __restrict__ W2,
    const float* __restrict__ B0, const float* __restrict__ B1, const float* __restrict__ B2,
    u16* __restrict__ Cq, u16* __restrict__ Ck, u16* __restrict__ Cvt)
{
    constexpr int K = 2048, N = 2048, NT = K / 32;
    const int z = blockIdx.z;
    const u16* W      = (z == 0) ? W0 : ((z == 1) ? W1 : W2);
    const float* bias = (z == 0) ? B0 : ((z == 1) ? B1 : B2);
    const int m0 = blockIdx.y * 128, n0 = blockIdx.x * 128;

    __shared__ __attribute__((aligned(16))) u16 As[3][128 * 32];
    __shared__ __attribute__((aligned(16))) u16 Bs[3][128 * 32];

    const int tid = threadIdx.x, l = tid & 63, w = tid >> 6;
    const int quad = l >> 4, lan = l & 15;

    const int sr = l >> 2, gcol = l & 3;
    const int gs0 = (gcol ^ ((w * 8 + (sr >> 2)) & 3)) * 8;
    const int gs1 = (gcol ^ ((w * 8 + 4 + (sr >> 2)) & 3)) * 8;
    const u16* pA0 = A + (size_t)(m0 + w * 32 + sr) * K + gs0;
    const u16* pA1 = A + (size_t)(m0 + w * 32 + 16 + sr) * K + gs1;
    const u16* pB0 = W + (size_t)(n0 + w * 32 + sr) * K + gs0;
    const u16* pB1 = W + (size_t)(n0 + w * 32 + 16 + sr) * K + gs1;
    const int dA0 = (w * 32) * 32;
    const int dA1 = (w * 32 + 16) * 32;

    const int wm = (w >> 1) * 64, wn = (w & 1) * 64;
    const int swq = (quad ^ ((lan >> 2) & 3)) * 8;

    f32x4 acc[4][4] = {};

    {
        g2l16(pA0, &As[0][dA0]); g2l16(pA1, &As[0][dA1]);
        g2l16(pB0, &Bs[0][dA0]); g2l16(pB1, &Bs[0][dA1]);
        g2l16(pA0 + 32, &As[1][dA0]); g2l16(pA1 + 32, &As[1][dA1]);
        g2l16(pB0 + 32, &Bs[1][dA0]); g2l16(pB1 + 32, &Bs[1][dA1]);
    }
    __asm__ volatile("s_waitcnt vmcnt(4)" ::: "memory");
    __builtin_amdgcn_s_barrier();
    __builtin_amdgcn_sched_barrier(0);

    int bc = 0;
    for (int t = 0; t < NT; ++t) {
        int bi = bc + 2; if (bi >= 3) bi -= 3;
        if (t + 2 < NT) {
            const int kk = (t + 2) * 32;
            g2l16(pA0 + kk, &As[bi][dA0]); g2l16(pA1 + kk, &As[bi][dA1]);
            g2l16(pB0 + kk, &Bs[bi][dA0]); g2l16(pB1 + kk, &Bs[bi][dA1]);
        }

        const u16* Ab = As[bc];
        const u16* Bb = Bs[bc];
        f16x8 af[4], bf[4];
#pragma unroll
        for (int i = 0; i < 4; i++)
            af[i] = __builtin_bit_cast(f16x8, *(const u16x8*)(&Ab[(wm + i * 16 + lan) * 32 + swq]));
#pragma unroll
        for (int j = 0; j < 4; j++)
            bf[j] = __builtin_bit_cast(f16x8, *(const u16x8*)(&Bb[(wn + j * 16 + lan) * 32 + swq]));

        __builtin_amdgcn_s_setprio(1);
#pragma unroll
        for (int i = 0; i < 4; i++)
#pragma unroll
            for (int j = 0; j < 4; j++)
                acc[i][j] = __builtin_amdgcn_mfma_f32_16x16x32_f16(af[i], bf[j], acc[i][j], 0, 0, 0);
        __builtin_amdgcn_s_setprio(0);

        if (t + 1 < NT) {
            if (t + 2 < NT) { __asm__ volatile("s_waitcnt vmcnt(4)" ::: "memory"); }
            else            { __asm__ volatile("s_waitcnt vmcnt(0)" ::: "memory"); }
            __builtin_amdgcn_s_barrier();
            __builtin_amdgcn_sched_barrier(0);
        }
        bc = (bc == 2) ? 0 : bc + 1;
    }

    if (z < 2) {
        u16* C = (z == 0) ? Cq : Ck;
#pragma unroll
        for (int j = 0; j < 4; j++) {
            const int col = n0 + wn + j * 16 + lan;
            const float bj = bias[col];
#pragma unroll
            for (int i = 0; i < 4; i++)
#pragma unroll
                for (int r = 0; r < 4; r++) {
                    const int row = m0 + wm + i * 16 + quad * 4 + r;
                    C[(size_t)row * N + col] = f2h(acc[i][j][r] + bj);
                }
        }
    } else {
        // V transposed: row=(b,s), col=(h,d) -> Cvt[((b*16+h)*128+d)*2048 + s]
#pragma unroll
        for (int j = 0; j < 4; j++) {
            const int col = n0 + wn + j * 16 + lan;
            const int hh = col >> 7, dd = col & 127;
            const float bj = bias[col];
            u16* Cr = Cvt + ((size_t)hh * 128 + dd) * 2048;
#pragma unroll
            for (int i = 0; i < 4; i++) {
                const int row0 = m0 + wm + i * 16 + quad * 4;
                const int bb = row0 >> 11, ss = row0 & 2047;
                u16x4 pv;
#pragma unroll
                for (int r = 0; r < 4; r++) pv[r] = f2h(acc[i][j][r] + bj);
                *(u16x4*)(Cr + (size_t)bb * 4194304 + ss) = pv;
            }
        }
    }
}

// ---------------------------------------------------------------------------
// RMSNorm + RoPE + history key scale; in-place f16 q/k; q *= 1/sqrt(128).
// ---------------------------------------------------------------------------
__global__ __launch_bounds__(256) void norm_rope(
    u16* __restrict__ q, u16* __restrict__ k,
    const float* __restrict__ rot,
    const float* __restrict__ nqw, const float* __restrict__ nkw,
    const float* __restrict__ hks, const int* __restrict__ oclp)
{
    const int row = blockIdx.x;
    const int s = row & 2047;
    const int t = threadIdx.x;
    const size_t base = (size_t)row * 2048 + t * 8;

    u16x8 q8 = *(const u16x8*)(q + base);
    u16x8 k8 = *(const u16x8*)(k + base);

    float qf[8], kf[8];
    float sq = 0.f, sk = 0.f;
#pragma unroll
    for (int i = 0; i < 8; i++) {
        qf[i] = h2f(q8[i]); sq += qf[i] * qf[i];
        kf[i] = h2f(k8[i]); sk += kf[i] * kf[i];
    }
#pragma unroll
    for (int off = 32; off > 0; off >>= 1) {
        sq += __shfl_down(sq, off);
        sk += __shfl_down(sk, off);
    }
    __shared__ float rq[4], rk[4];
    const int wv = t >> 6;
    if ((t & 63) == 0) { rq[wv] = sq; rk[wv] = sk; }
    __syncthreads();
    const float tq = rq[0] + rq[1] + rq[2] + rq[3];
    const float tk = rk[0] + rk[1] + rk[2] + rk[3];
    const float scq = rsqrtf(tq * (1.0f / 2048.0f) + 1e-5f);
    const float sck = rsqrtf(tk * (1.0f / 2048.0f) + 1e-5f);
#pragma unroll
    for (int i = 0; i < 8; i++) {
        qf[i] *= scq * nqw[t * 8 + i];
        kf[i] *= sck * nkw[t * 8 + i];
    }
    const int e0 = t * 8;
    const int dh0 = e0 & 127;
    const int h = e0 >> 7;
    float qo[8], ko[8];
#pragma unroll
    for (int p = 0; p < 4; p++) {
        const int dh = dh0 + 2 * p;
        const float c  = rot[s * 256 + dh];
        const float sn = rot[s * 256 + 128 + dh + 1];
        qo[2 * p]     = qf[2 * p] * c  - qf[2 * p + 1] * sn;
        qo[2 * p + 1] = qf[2 * p] * sn + qf[2 * p + 1] * c;
        ko[2 * p]     = kf[2 * p] * c  - kf[2 * p + 1] * sn;
        ko[2 * p + 1] = kf[2 * p] * sn + kf[2 * p + 1] * c;
    }
    const float ATT = 0.08838834764831845f;
#pragma unroll
    for (int i = 0; i < 8; i++) qo[i] *= ATT;

    const int hist = 2048 - oclp[0];
    if (s < hist) {
        const float hv = hks[h];
        const float scl = 1.0f + 9.0f / (1.0f + expf(-hv));
#pragma unroll
        for (int i = 0; i < 8; i++) ko[i] *= scl;
    }

    u16x8 qo8, ko8;
#pragma unroll
    for (int i = 0; i < 8; i++) { qo8[i] = f2h(qo[i]); ko8[i] = f2h(ko[i]); }
    *(u16x8*)(q + base) = qo8;
    *(u16x8*)(k + base) = ko8;
}

// ---------------------------------------------------------------------------
// Flash attention v6: v5 + 32 q-rows per wave (QBLK=128/block, grid 16x32).
// Each K-tile / V^T-tile LDS read is reused across TWO q-groups -> FLOP per
// LDS-byte doubles (12.2 -> 24). kb/vtf read once, 2 MFMA each.
// LDS = 16(K) + 16(VT) + 10(P) = 42 KB -> 3 blocks/CU.
// ---------------------------------------------------------------------------
__global__ __launch_bounds__(256, 4) void flash_attn6(
    const u16* __restrict__ Q, const u16* __restrict__ Kr, const u16* __restrict__ Vt,
    u16* __restrict__ O)
{
    const int qt = blockIdx.x;        // 0..15 (128 q-rows each)
    const int bh = blockIdx.y;        // 0..31
    const int b = bh >> 4, h = bh & 15;
    const int tid = threadIdx.x, l = tid & 63, w = tid >> 6;
    const int quad = l >> 4, lan = l & 15;

    __shared__ __attribute__((aligned(16))) u16 Kb[2][32 * 128];
    __shared__ __attribute__((aligned(16))) u16 VTb[2][128 * 32];
    __shared__ __attribute__((aligned(16))) u16 Pb[4][32 * 40];

    // Q frags for both q-groups (rows w*32 + g*16 + lan); pre-scaled by ATT
    f16x8 qf0[4], qf1[4];
    {
        const u16* qp = Q + ((size_t)(b * 2048 + qt * 128 + w * 32 + lan)) * 2048 + h * 128 + quad * 8;
#pragma unroll
        for (int ks = 0; ks < 4; ks++) {
            qf0[ks] = __builtin_bit_cast(f16x8, *(const u16x8*)(qp + ks * 32));
            qf1[ks] = __builtin_bit_cast(f16x8, *(const u16x8*)(qp + 16 * 2048 + ks * 32));
        }
    }

    // K staging: 2 issues; issue i: row = w*4 + 16i + (l>>4), chunk l&15,
    // source chunk XOR'd by row&15. LDS layout [32][128] row-major.
    const int krow_b = w * 4 + (l >> 4);
    const int kchk   = l & 15;
    const u16* kbase = Kr + ((size_t)(b * 2048)) * 2048 + h * 128;
    // VT staging: 2 issues; row = w*16 + 64i + (l>>2), chunk l&3,
    // source chunk XOR'd by ((row mod 16)>>1)&3 = (l>>3)&3. LDS [128][32].
    const int vrow_b = w * 16 + (l >> 2);
    const int vg     = ((l & 3) ^ ((l >> 3) & 3)) * 8;
    const u16* vbase = Vt + ((size_t)((b * 16 + h) * 128)) * 2048;

    float mr0 = -3.0e38f, lrp0 = 0.f;
    float mr1 = -3.0e38f, lrp1 = 0.f;
    f32x4 o0[8] = {}, o1[8] = {};

    // issue DMA for tile 0 into buf 0
#pragma unroll
    for (int i = 0; i < 2; i++) {
        const int kr = krow_b + 16 * i;
        g2l16(kbase + (size_t)kr * 2048 + ((kchk ^ (kr & 15)) * 8), &Kb[0][(w * 64 + 256 * i) * 8]);
    }
#pragma unroll
    for (int i = 0; i < 2; i++) {
        const int vr = vrow_b + 64 * i;
        g2l16(vbase + (size_t)vr * 2048 + vg, &VTb[0][(w * 64 + 256 * i) * 8]);
    }
    __syncthreads();   // drain tile-0 DMA

    for (int kt = 0; kt < 64; kt++) {
        const int buf = kt & 1;
        // prefetch tile kt+1 into other buffer (completes during compute)
        if (kt < 63) {
            const int kn = (kt + 1) * 32;
#pragma unroll
            for (int i = 0; i < 2; i++) {
                const int kr = krow_b + 16 * i;
                g2l16(kbase + (size_t)(kn + kr) * 2048 + ((kchk ^ (kr & 15)) * 8),
                      &Kb[buf ^ 1][(w * 64 + 256 * i) * 8]);
            }
#pragma unroll
            for (int i = 0; i < 2; i++) {
                const int vr = vrow_b + 64 * i;
                g2l16(vbase + (size_t)vr * 2048 + kn + vg,
                      &VTb[buf ^ 1][(w * 64 + 256 * i) * 8]);
            }
        }

        // S^T = K Q^T : kb read once, used for BOTH q-groups
        f32x4 s0[2] = {}, s1[2] = {};
        __builtin_amdgcn_s_setprio(1);
#pragma unroll
        for (int ks = 0; ks < 4; ks++)
#pragma unroll
            for (int nt = 0; nt < 2; nt++) {
                f16x8 kb = __builtin_bit_cast(f16x8, *(const u16x8*)(
                    &Kb[buf][(nt * 16 + lan) * 128 + (((ks * 4 + quad) ^ lan) * 8)]));
                s0[nt] = __builtin_amdgcn_mfma_f32_16x16x32_f16(kb, qf0[ks], s0[nt], 0, 0, 0);
                s1[nt] = __builtin_amdgcn_mfma_f32_16x16x32_f16(kb, qf1[ks], s1[nt], 0, 0, 0);
            }
        __builtin_amdgcn_s_setprio(0);

        // per-lane scalar online softmax, per q-group
        float tm0 = fmaxf(fmaxf(fmaxf(s0[0][0], s0[0][1]), fmaxf(s0[0][2], s0[0][3])),
                          fmaxf(fmaxf(s0[1][0], s0[1][1]), fmaxf(s0[1][2], s0[1][3])));
        float tm1 = fmaxf(fmaxf(fmaxf(s1[0][0], s1[0][1]), fmaxf(s1[0][2], s1[0][3])),
                          fmaxf(fmaxf(s1[1][0], s1[1][1]), fmaxf(s1[1][2], s1[1][3])));
        tm0 = fmaxf(tm0, __shfl_xor(tm0, 16)); tm0 = fmaxf(tm0, __shfl_xor(tm0, 32));
        tm1 = fmaxf(tm1, __shfl_xor(tm1, 16)); tm1 = fmaxf(tm1, __shfl_xor(tm1, 32));

        if (!__all(tm0 <= mr0 + 4.0f)) {
            const float nm = fmaxf(mr0, tm0);
            const float al = exp2f((mr0 - nm) * LOG2E);
            mr0 = nm; lrp0 *= al;
#pragma unroll
            for (int nd = 0; nd < 8; nd++)
#pragma unroll
                for (int r = 0; r < 4; r++) o0[nd][r] *= al;
        }
        if (!__all(tm1 <= mr1 + 4.0f)) {
            const float nm = fmaxf(mr1, tm1);
            const float al = exp2f((mr1 - nm) * LOG2E);
            mr1 = nm; lrp1 *= al;
#pragma unroll
            for (int nd = 0; nd < 8; nd++)
#pragma unroll
                for (int r = 0; r < 4; r++) o1[nd][r] *= al;
        }

        float ps0 = 0.f, ps1 = 0.f;
        u16x4 a0, a1, b0, b1;
#pragma unroll
        for (int r = 0; r < 4; r++) {
            float p = exp2f((s0[0][r] - mr0) * LOG2E); ps0 += p; a0[r] = f2h(p);
            p = exp2f((s0[1][r] - mr0) * LOG2E);       ps0 += p; a1[r] = f2h(p);
            p = exp2f((s1[0][r] - mr1) * LOG2E);       ps1 += p; b0[r] = f2h(p);
            p = exp2f((s1[1][r] - mr1) * LOG2E);       ps1 += p; b1[r] = f2h(p);
        }
        lrp0 += ps0; lrp1 += ps1;

        // stage P[q_local][k]: q_local = g*16 + lan, 32 k per row (+8 pad)
        *(u16x4*)(&Pb[w][lan * 40 + quad * 4])             = a0;
        *(u16x4*)(&Pb[w][lan * 40 + 16 + quad * 4])        = a1;
        *(u16x4*)(&Pb[w][(16 + lan) * 40 + quad * 4])      = b0;
        *(u16x4*)(&Pb[w][(16 + lan) * 40 + 16 + quad * 4]) = b1;

        __asm__ volatile("s_waitcnt lgkmcnt(0)" ::: "memory");  // own-wave P visible

        // O^T += V^T P^T : vtf read once, used for BOTH q-groups
        f16x8 pf0 = __builtin_bit_cast(f16x8, *(const u16x8*)(&Pb[w][lan * 40 + quad * 8]));
        f16x8 pf1 = __builtin_bit_cast(f16x8, *(const u16x8*)(&Pb[w][(16 + lan) * 40 + quad * 8]));
        __builtin_amdgcn_s_setprio(1);
#pragma unroll
        for (int nd = 0; nd < 8; nd++) {
            f16x8 vtf = __builtin_bit_cast(f16x8, *(const u16x8*)(
                &VTb[buf][(nd * 16 + lan) * 32 + ((quad ^ ((lan >> 1) & 3)) * 8)]));
            o0[nd] = __builtin_amdgcn_mfma_f32_16x16x32_f16(vtf, pf0, o0[nd], 0, 0, 0);
            o1[nd] = __builtin_amdgcn_mfma_f32_16x16x32_f16(vtf, pf1, o1[nd], 0, 0, 0);
        }
        __builtin_amdgcn_s_setprio(0);

        __syncthreads();   // drains kt+1 DMA (had full compute to land) + syncs
    }

    // finalize deferred sums across quads (disjoint k-subsets)
    lrp0 += __shfl_xor(lrp0, 16); lrp0 += __shfl_xor(lrp0, 32);
    lrp1 += __shfl_xor(lrp1, 16); lrp1 += __shfl_xor(lrp1, 32);
    const float inv0 = 1.0f / lrp0;
    const float inv1 = 1.0f / lrp1;

    // O^T lane layout: q = lan, d = nd*16 + quad*4 + r
    u16* Or = O + ((size_t)(b * 2048 + qt * 128 + w * 32 + lan)) * 2048 + h * 128 + quad * 4;
#pragma unroll
    for (int nd = 0; nd < 8; nd++) {
        u16x4 ov;
#pragma unroll
        for (int r = 0; r < 4; r++) ov[r] = f2h(o0[nd][r] * inv0);
        *(u16x4*)(Or + nd * 16) = ov;
    }
    Or += (size_t)16 * 2048;
#pragma unroll
    for (int nd = 0; nd < 8; nd++) {
        u16x4 ov;
#pragma unroll
        for (int r = 0; r < 4; r++) ov[r] = f2h(o1[nd][r] * inv1);
        *(u16x4*)(Or + nd * 16) = ov;
    }
}

// ---------------------------------------------------------------------------
// Output projection v2: triple-buffered counted-vmcnt pipeline (unchanged).
// A = aout f16, B = Wo16 f16, C fp32.
// ---------------------------------------------------------------------------
__global__ __launch_bounds__(256, 4) void gemm_out(
    const u16* __restrict__ A, const u16* __restrict__ W,
    const float* __restrict__ bias, float* __restrict__ C)
{
    constexpr int K = 2048, N = 2048, NT = K / 32;
    const int m0 = blockIdx.y * 128, n0 = blockIdx.x * 128;

    __shared__ __attribute__((aligned(16))) u16 As[3][128 * 32];
    __shared__ __attribute__((aligned(16))) u16 Bs[3][128 * 32];

    const int tid = threadIdx.x, l = tid & 63, w = tid >> 6;
    const int quad = l >> 4, lan = l & 15;

    const int sr = l >> 2, gcol = l & 3;
    const int gs0 = (gcol ^ ((w * 8 + (sr >> 2)) & 3)) * 8;
    const int gs1 = (gcol ^ ((w * 8 + 4 + (sr >> 2)) & 3)) * 8;
    const u16* pA0 = A + (size_t)(m0 + w * 32 + sr) * K + gs0;
    const u16* pA1 = A + (size_t)(m0 + w * 32 + 16 + sr) * K + gs1;
    const u16* pB0 = W + (size_t)(n0 + w * 32 + sr) * K + gs0;
    const u16* pB1 = W + (size_t)(n0 + w * 32 + 16 + sr) * K + gs1;
    const int dA0 = (w * 32) * 32;
    const int dA1 = (w * 32 + 16) * 32;

    const int wm = (w >> 1) * 64, wn = (w & 1) * 64;
    const int swq = (quad ^ ((lan >> 2) & 3)) * 8;

    f32x4 acc[4][4] = {};

    {
        g2l16(pA0, &As[0][dA0]); g2l16(pA1, &As[0][dA1]);
        g2l16(pB0, &Bs[0][dA0]); g2l16(pB1, &Bs[0][dA1]);
        g2l16(pA0 + 32, &As[1][dA0]); g2l16(pA1 + 32, &As[1][dA1]);
        g2l16(pB0 + 32, &Bs[1][dA0]); g2l16(pB1 + 32, &Bs[1][dA1]);
    }
    __asm__ volatile("s_waitcnt vmcnt(4)" ::: "memory");
    __builtin_amdgcn_s_barrier();
    __builtin_amdgcn_sched_barrier(0);

    int bc = 0;
    for (int t = 0; t < NT; ++t) {
        int bi = bc + 2; if (bi >= 3) bi -= 3;
        if (t + 2 < NT) {
            const int kk = (t + 2) * 32;
            g2l16(pA0 + kk, &As[bi][dA0]); g2l16(pA1 + kk, &As[bi][dA1]);
            g2l16(pB0 + kk, &Bs[bi][dA0]); g2l16(pB1 + kk, &Bs[bi][dA1]);
        }

        const u16* Ab = As[bc];
        const u16* Bb = Bs[bc];
        f16x8 af[4], bf[4];
#pragma unroll
        for (int i = 0; i < 4; i++)
            af[i] = __builtin_bit_cast(f16x8, *(const u16x8*)(&Ab[(wm + i * 16 + lan) * 32 + swq]));
#pragma unroll
        for (int j = 0; j < 4; j++)
            bf[j] = __builtin_bit_cast(f16x8, *(const u16x8*)(&Bb[(wn + j * 16 + lan) * 32 + swq]));

        __builtin_amdgcn_s_setprio(1);
#pragma unroll
        for (int i = 0; i < 4; i++)
#pragma unroll
            for (int j = 0; j < 4; j++)
                acc[i][j] = __builtin_amdgcn_mfma_f32_16x16x32_f16(af[i], bf[j], acc[i][j], 0, 0, 0);
        __builtin_amdgcn_s_setprio(0);

        if (t + 1 < NT) {
            if (t + 2 < NT) { __asm__ volatile("s_waitcnt vmcnt(4)" ::: "memory"); }
            else            { __asm__ volatile("s_waitcnt vmcnt(0)" ::: "memory"); }
            __builtin_amdgcn_s_barrier();
            __builtin_amdgcn_sched_barrier(0);
        }
        bc = (bc == 2) ? 0 : bc + 1;
    }

#pragma unroll
    for (int j = 0; j < 4; j++) {
        const int col = n0 + wn + j * 16 + lan;
        const float bj = bias[col];
#pragma unroll
        for (int i = 0; i < 4; i++)
#pragma unroll
            for (int r = 0; r < 4; r++) {
                const int row = m0 + wm + i * 16 + quad * 4 + r;
                C[(size_t)row * N + col] = acc[i][j][r] + bj;
            }
    }
}

// ---------------------------------------------------------------------------
extern "C" void kernel_launch(void* const* d_in, const int* in_sizes, int n_in,
                              void* d_out, int out_size, void* d_ws, size_t ws_size,
                              hipStream_t stream) {
    const float* hs  = (const float*)d_in[0];
    const float* rot = (const float*)d_in[1];
    const float* Wq  = (const float*)d_in[2];
    const float* bq  = (const float*)d_in[3];
    const float* Wk  = (const float*)d_in[4];
    const float* bk  = (const float*)d_in[5];
    const float* Wv  = (const float*)d_in[6];
    const float* bv  = (const float*)d_in[7];
    const float* nqw = (const float*)d_in[8];
    const float* nkw = (const float*)d_in[9];
    const float* hks = (const float*)d_in[10];
    const float* Wo  = (const float*)d_in[11];
    const float* bo  = (const float*)d_in[12];
    const int*   ocl = (const int*)d_in[13];

    // ws (64 MiB): [0:16) qraw | [16:32) kraw | [32:48) vtr | [48:64) aout
    // aout region holds Wq16/Wk16 until flash overwrites it (they're dead then).
    u16* qraw = (u16*)d_ws;
    u16* kraw = qraw + 8388608;
    u16* vtr  = kraw + 8388608;
    u16* aout = vtr + 8388608;
    u16* wq16 = aout;                  // [48:56 MiB)
    u16* wk16 = aout + 4194304;        // [56:64 MiB)
    u16* wo16 = qraw;                  // reuses qraw AFTER flash
    float* out = (float*)d_out;
    u16* hs16 = (u16*)d_out;           // d_out [0:16 MiB)
    u16* wv16 = hs16 + 8388608;        // d_out [16:24 MiB)

    // 0) convert hs + Wq/Wk/Wv to f16
    cvt4<<<dim3(10240), 256, 0, stream>>>(hs, Wq, Wk, Wv, hs16, wq16, wk16, wv16);
    // 1) QKV projection (triple-buffered counted-vmcnt); z=2 writes V^T
    gemm_qkv<<<dim3(16, 32, 3), 256, 0, stream>>>(
        hs16, wq16, wk16, wv16, bq, bk, bv, qraw, kraw, vtr);
    // 2) rmsnorm + rope + history scale
    norm_rope<<<dim3(4096), 256, 0, stream>>>(qraw, kraw, rot, nqw, nkw, hks, ocl);
    // 3) flash attention v6 (32 q/wave, 2x LDS reuse) -> aout
    flash_attn6<<<dim3(16, 32), 256, 0, stream>>>(qraw, kraw, vtr, aout);
    // 4) Wo -> f16 into dead qraw region, then output projection -> d_out
    cvt1<<<dim3(2048), 256, 0, stream>>>(Wo, wo16);
    gemm_out<<<dim3(16, 32), 256, 0, stream>>>(aout, wo16, bo, out);
}